// Round 2
// baseline (12052.225 us; speedup 1.0000x reference)
//
#include <hip/hip_runtime.h>
#include <hip/hip_fp16.h>
#include <cstddef>

#define T_LEN 4096
#define HID 150
#define G4 600
#define NC 300

// raw barrier: waits LDS ops only, leaves global loads/stores in flight
__device__ __forceinline__ void barrier_lgkm() {
  asm volatile("s_waitcnt lgkmcnt(0)\n\ts_barrier" ::: "memory");
}

__device__ __forceinline__ float fsig(float x) {
  return __builtin_amdgcn_rcpf(1.f + __expf(-x));
}
__device__ __forceinline__ float ftanh(float x) {
  float ax = fabsf(x);
  float e = __expf(2.f * ax);
  float t = 1.f - 2.f * __builtin_amdgcn_rcpf(e + 1.f);
  return copysignf(t, x);
}

// ---------------- LSTM scan: 4 chains (net x dir), one block each --------------
// block 1024: tid = kt*128 + jt ; thread owns gates j = jt+128q (q<5), k in [kt*20, kt*20+20)
// 100 weight floats/thread -> fits 128-VGPR budget at 4 waves/SIMD (no spill).
constexpr int SC_KT = 8, SC_KC = 20, SC_NQ = 5;

__global__ __launch_bounds__(1024, 4) void lstm_scan(
    const float* __restrict__ whh_solv, const float* __restrict__ whh_solu,
    const float* __restrict__ xg_base,
    float* __restrict__ out_solv, float* __restrict__ out_solu, int layer)
{
  __shared__ __align__(16) float h_s[SC_KT * SC_KC];   // 160 floats, zeros beyond 150
  __shared__ float pbuf[640][SC_KT + 1];               // stride 9 (odd): conflict-free
  const int c = blockIdx.x;
  const int net = c >> 1, dir = c & 1;
  const float* Whh = (net ? whh_solu : whh_solv) + (size_t)(layer * 2 + dir) * (G4 * HID);
  const float* xg = xg_base + (size_t)c * T_LEN * G4;
  float* out = (net ? out_solu : out_solv) + dir * HID;  // row stride NC
  const int tid = threadIdx.x;
  const int kt = tid >> 7, jt = tid & 127;
  const int k0 = kt * SC_KC;

  // weights -> registers (one-time)
  float w[SC_NQ][SC_KC];
#pragma unroll
  for (int q = 0; q < SC_NQ; q++) {
    const int j = jt + 128 * q;
    const bool jv = (j < G4);
#pragma unroll
    for (int i = 0; i < SC_KC; i++) {
      const int k = k0 + i;
      w[q][i] = (jv && k < HID) ? Whh[(size_t)j * HID + k] : 0.f;
    }
  }
  if (tid < SC_KT * SC_KC) h_s[tid] = 0.f;
  float cst = 0.f;
  float xr0 = 0.f, xr1 = 0.f, xr2 = 0.f, xr3 = 0.f;
  if (tid < HID) {
    const int t0 = dir ? (T_LEN - 1) : 0;
    const float* xgr = xg + (size_t)t0 * G4 + tid;
    xr0 = xgr[0]; xr1 = xgr[HID]; xr2 = xgr[2 * HID]; xr3 = xgr[3 * HID];
  }
  barrier_lgkm();

  for (int s = 0; s < T_LEN; s++) {
    const int t = dir ? (T_LEN - 1 - s) : s;
    float acc[SC_NQ] = {0.f, 0.f, 0.f, 0.f, 0.f};
#pragma unroll
    for (int i = 0; i < SC_KC; i += 4) {
      const float4 hv = *(const float4*)&h_s[k0 + i];   // wave-broadcast read
#pragma unroll
      for (int q = 0; q < SC_NQ; q++)
        acc[q] += w[q][i] * hv.x + w[q][i + 1] * hv.y + w[q][i + 2] * hv.z + w[q][i + 3] * hv.w;
    }
#pragma unroll
    for (int q = 0; q < SC_NQ; q++) pbuf[jt + 128 * q][kt] = acc[q];
    barrier_lgkm();
    if (tid < HID) {
      const int n = tid;
      float gi = xr0, gf = xr1, gg = xr2, go = xr3;
#pragma unroll
      for (int kk = 0; kk < SC_KT; kk++) {
        gi += pbuf[n][kk];
        gf += pbuf[HID + n][kk];
        gg += pbuf[2 * HID + n][kk];
        go += pbuf[3 * HID + n][kk];
      }
      if (s + 1 < T_LEN) {  // prefetch next xg row (consumed next step; barrier leaves it in flight)
        const int tn = dir ? (T_LEN - 2 - s) : (s + 1);
        const float* xgr = xg + (size_t)tn * G4 + n;
        xr0 = xgr[0]; xr1 = xgr[HID]; xr2 = xgr[2 * HID]; xr3 = xgr[3 * HID];
      }
      const float iv = fsig(gi), fv = fsig(gf), gv = ftanh(gg), ov = fsig(go);
      cst = fv * cst + iv * gv;
      const float hv = ov * ftanh(cst);
      h_s[n] = hv;
      out[(size_t)t * NC + n] = hv;
    }
    barrier_lgkm();
  }
}

// ---------------- generic tiled fp32 GEMM -------------------------------------
// MODE: 0 = NT (C=A*B^T), 1 = NN, 2 = TN.  EPI: 0 = float C (+bias e0[n]+e1[n] if e0),
// 1 = half C = exp(acc - e0[m]) * e1[m]
__device__ __forceinline__ float to_f(float v) { return v; }
__device__ __forceinline__ float to_f(__half v) { return __half2float(v); }

#define LP 68  // LDS row pitch: 272 B (16B-aligned rows, breaks stride-64 bank conflicts)

template <int MODE, typename TA, int EPI>
__global__ void gemm_k(const TA* __restrict__ A, const float* __restrict__ B,
                       void* __restrict__ Cv, int M, int N, int K,
                       int lda, int ldb, int ldc,
                       const float* __restrict__ e0, const float* __restrict__ e1)
{
  __shared__ __align__(16) float As[16][LP];
  __shared__ __align__(16) float Bs[16][LP];
  const int tid = threadIdx.x;
  const int tx = tid & 15, ty = tid >> 4;
  const int m0 = blockIdx.y * 64, n0 = blockIdx.x * 64;
  float acc[4][4] = {};
  for (int kc = 0; kc < K; kc += 16) {
#pragma unroll
    for (int j = 0; j < 4; j++) {
      const int li = tid * 4 + j;
      int ml, kl;
      if (MODE == 2) { ml = li & 63; kl = li >> 6; }
      else           { ml = li >> 4; kl = li & 15; }
      const int m = m0 + ml, k = kc + kl;
      float v = 0.f;
      if (m < M && k < K)
        v = to_f(MODE == 2 ? A[(size_t)k * lda + m] : A[(size_t)m * lda + k]);
      As[kl][ml] = v;
    }
#pragma unroll
    for (int j = 0; j < 4; j++) {
      const int li = tid * 4 + j;
      int nl, kl;
      if (MODE == 0) { nl = li >> 4; kl = li & 15; }
      else           { nl = li & 63; kl = li >> 6; }
      const int n = n0 + nl, k = kc + kl;
      float v = 0.f;
      if (n < N && k < K)
        v = (MODE == 0) ? B[(size_t)n * ldb + k] : B[(size_t)k * ldb + n];
      Bs[kl][nl] = v;
    }
    __syncthreads();
#pragma unroll
    for (int kl = 0; kl < 16; kl++) {
      const float4 av = *(const float4*)&As[kl][ty * 4];
      const float4 bv = *(const float4*)&Bs[kl][tx * 4];
      const float aa[4] = {av.x, av.y, av.z, av.w};
      const float bb[4] = {bv.x, bv.y, bv.z, bv.w};
#pragma unroll
      for (int i = 0; i < 4; i++)
#pragma unroll
        for (int jj = 0; jj < 4; jj++)
          acc[i][jj] += aa[i] * bb[jj];
    }
    __syncthreads();
  }
#pragma unroll
  for (int i = 0; i < 4; i++) {
    const int m = m0 + ty * 4 + i;
    if (m >= M) continue;
#pragma unroll
    for (int j = 0; j < 4; j++) {
      const int n = n0 + tx * 4 + j;
      if (n >= N) continue;
      if (EPI == 0) {
        float v = acc[i][j];
        if (e0) v += e0[n] + e1[n];
        ((float*)Cv)[(size_t)m * ldc + n] = v;
      } else {
        const float v = __expf(acc[i][j] - e0[m]) * e1[m];
        ((__half*)Cv)[(size_t)m * ldc + n] = __float2half(v);
      }
    }
  }
}

// ------------- attention softmax stats (never materializes S) -----------------
// grid (8 g-chunks, 64 h-blocks), block 256; writes partial (m,l) per row per chunk
__global__ void attn_stats(const float* __restrict__ Hm, const float* __restrict__ Gm,
                           float* __restrict__ pm, float* __restrict__ pl)
{
  __shared__ __align__(16) float As[16][LP];
  __shared__ __align__(16) float Bs[16][LP];
  const int tid = threadIdx.x;
  const int tx = tid & 15, ty = tid >> 4;
  const int m0 = blockIdx.y * 64;
  float rm[4], rl[4];
#pragma unroll
  for (int i = 0; i < 4; i++) { rm[i] = -3e38f; rl[i] = 0.f; }
  for (int nt = 0; nt < 8; nt++) {
    const int n0 = (blockIdx.x * 8 + nt) * 64;
    float acc[4][4] = {};
    for (int kc = 0; kc < NC; kc += 16) {
#pragma unroll
      for (int j = 0; j < 4; j++) {
        const int li = tid * 4 + j;
        const int ml = li >> 4, kl = li & 15;
        const int k = kc + kl;
        As[kl][ml] = (k < NC) ? Hm[(size_t)(m0 + ml) * NC + k] : 0.f;
        Bs[kl][ml] = (k < NC) ? Gm[(size_t)(n0 + ml) * NC + k] : 0.f;
      }
      __syncthreads();
#pragma unroll
      for (int kl = 0; kl < 16; kl++) {
        const float4 av = *(const float4*)&As[kl][ty * 4];
        const float4 bv = *(const float4*)&Bs[kl][tx * 4];
        const float aa[4] = {av.x, av.y, av.z, av.w};
        const float bb[4] = {bv.x, bv.y, bv.z, bv.w};
#pragma unroll
        for (int i = 0; i < 4; i++)
#pragma unroll
          for (int jj = 0; jj < 4; jj++)
            acc[i][jj] += aa[i] * bb[jj];
      }
      __syncthreads();
    }
#pragma unroll
    for (int i = 0; i < 4; i++) {
      const float mx = fmaxf(fmaxf(acc[i][0], acc[i][1]), fmaxf(acc[i][2], acc[i][3]));
      const float nm = fmaxf(rm[i], mx);
      const float s = __expf(acc[i][0] - nm) + __expf(acc[i][1] - nm) +
                      __expf(acc[i][2] - nm) + __expf(acc[i][3] - nm);
      rl[i] = rl[i] * __expf(rm[i] - nm) + s;
      rm[i] = nm;
    }
  }
  __syncthreads();
#pragma unroll
  for (int i = 0; i < 4; i++) { As[tx][ty * 4 + i] = rm[i]; Bs[tx][ty * 4 + i] = rl[i]; }
  __syncthreads();
  if (tid < 64) {
    float m = As[0][tid], l = Bs[0][tid];
#pragma unroll
    for (int c2 = 1; c2 < 16; c2++) {
      const float m2 = As[c2][tid], l2 = Bs[c2][tid];
      const float nm = fmaxf(m, m2);
      l = l * __expf(m - nm) + l2 * __expf(m2 - nm);
      m = nm;
    }
    pm[(size_t)(m0 + tid) * 8 + blockIdx.x] = m;
    pl[(size_t)(m0 + tid) * 8 + blockIdx.x] = l;
  }
}

__global__ void stats_combine(const float* __restrict__ pm, const float* __restrict__ pl,
                              float* __restrict__ mrow, float* __restrict__ invl)
{
  const int r = blockIdx.x * 256 + threadIdx.x;
  float m = -3e38f;
#pragma unroll
  for (int c2 = 0; c2 < 8; c2++) m = fmaxf(m, pm[r * 8 + c2]);
  float l = 0.f;
#pragma unroll
  for (int c2 = 0; c2 < 8; c2++) l += pl[r * 8 + c2] * __expf(pm[r * 8 + c2] - m);
  mrow[r] = m;
  invl[r] = 1.f / l;
}

// ---------------- tail ---------------------------------------------------------
__global__ void zero_inp(float* __restrict__ inp) {
  if (threadIdx.x < 600) inp[threadIdx.x] = 0.f;
}

__global__ void reduce_uv(const float* __restrict__ X, const float* __restrict__ Yp,
                          float* __restrict__ inp, int off)
{
  const int j = threadIdx.x;
  if (j >= NC) return;
  const int r0 = blockIdx.x * 128;
  float s = 0.f;
  for (int r = r0; r < r0 + 128; r++)
    s += fmaxf(X[(size_t)r * NC + j], Yp[(size_t)r * NC + j]);
  atomicAdd(&inp[off + j], s);
}

__global__ void fc1_k(const float* __restrict__ w1, const float* __restrict__ b1,
                      const float* __restrict__ inp, float* __restrict__ x)
{
  const int r = blockIdx.x * 256 + threadIdx.x;
  if (r >= 2000) return;
  float s = b1[r];
  const float* wr = w1 + (size_t)r * 600;
  for (int k = 0; k < 600; k++) s += wr[k] * inp[k];
  x[r] = fmaxf(s, 0.f);
}

__global__ void fc2_k(const float* __restrict__ x, const float* __restrict__ w2,
                      const float* __restrict__ b2, float* __restrict__ outp)
{
  const int tid = threadIdx.x;
  float s = 0.f;
  for (int i = tid; i < 2000; i += 256) s += x[i] * w2[i];
#pragma unroll
  for (int off = 32; off > 0; off >>= 1) s += __shfl_down(s, off);
  __shared__ float red[4];
  if ((tid & 63) == 0) red[tid >> 6] = s;
  __syncthreads();
  if (tid == 0) outp[0] = red[0] + red[1] + red[2] + red[3] + b2[0];
}

// ---------------- launch --------------------------------------------------------
extern "C" void kernel_launch(void* const* d_in, const int* in_sizes, int n_in,
                              void* d_out, int out_size, void* d_ws, size_t ws_size,
                              hipStream_t stream)
{
  const float* in_solv  = (const float*)d_in[0];
  const float* in_solu  = (const float*)d_in[1];
  const float* solv_Wih = (const float*)d_in[2];
  const float* solv_Whh = (const float*)d_in[3];
  const float* solv_bih = (const float*)d_in[4];
  const float* solv_bhh = (const float*)d_in[5];
  const float* solu_Wih = (const float*)d_in[6];
  const float* solu_Whh = (const float*)d_in[7];
  const float* solu_bih = (const float*)d_in[8];
  const float* solu_bhh = (const float*)d_in[9];
  const float* fc1_w = (const float*)d_in[10];
  const float* fc1_b = (const float*)d_in[11];
  const float* fc2_w = (const float*)d_in[12];
  const float* fc2_b = (const float*)d_in[13];
  float* outp = (float*)d_out;
  float* ws = (float*)d_ws;

  // workspace layout (float offsets); AH(half) aliases dead xg region. total ~69 MB
  constexpr size_t off_P   = 0;
  constexpr size_t off_Q   = 1228800;
  constexpr size_t off_inp = 2457600;
  constexpr size_t off_x   = 2458240;
  constexpr size_t off_pm  = 2460288;
  constexpr size_t off_pl  = 2493056;
  constexpr size_t off_mr  = 2525824;
  constexpr size_t off_il  = 2529920;
  constexpr size_t off_xg  = 2534016;
  constexpr size_t off_L0  = off_xg + (size_t)4 * 2457600;
  constexpr size_t off_HG  = off_L0 + (size_t)2 * 1228800;

  float* xg  = ws + off_xg;
  float* L0v = ws + off_L0;
  float* L0u = L0v + 1228800;
  float* Hb  = ws + off_HG;
  float* Gb  = Hb + 1228800;
  float* Pb  = ws + off_P;
  float* Qb  = ws + off_Q;
  float* inp = ws + off_inp;
  float* xf  = ws + off_x;
  float* pm  = ws + off_pm;
  float* pl  = ws + off_pl;
  float* mr  = ws + off_mr;
  float* il  = ws + off_il;
  __half* AH = (__half*)(ws + off_xg);

  // layer 0: xg = X @ Wih^T + (bih+bhh), 4 chains
  for (int c = 0; c < 4; c++) {
    const int net = c >> 1, d = c & 1;
    const float* X   = net ? in_solu : in_solv;
    const float* Wih = (net ? solu_Wih : solv_Wih) + (size_t)d * (600 * 300);
    const float* bi  = (net ? solu_bih : solv_bih) + (size_t)d * 600;
    const float* bh  = (net ? solu_bhh : solv_bhh) + (size_t)d * 600;
    gemm_k<0, float, 0><<<dim3(10, 64), 256, 0, stream>>>(
        X, Wih, (void*)(xg + (size_t)c * 2457600), 4096, 600, 300, 300, 300, 600, bi, bh);
  }
  lstm_scan<<<4, 1024, 0, stream>>>(solv_Whh, solu_Whh, xg, L0v, L0u, 0);

  // layer 1
  for (int c = 0; c < 4; c++) {
    const int net = c >> 1, d = c & 1;
    const float* X   = net ? L0u : L0v;
    const float* Wih = (net ? solu_Wih : solv_Wih) + (size_t)(2 + d) * (600 * 300);
    const float* bi  = (net ? solu_bih : solv_bih) + (size_t)(2 + d) * 600;
    const float* bh  = (net ? solu_bhh : solv_bhh) + (size_t)(2 + d) * 600;
    gemm_k<0, float, 0><<<dim3(10, 64), 256, 0, stream>>>(
        X, Wih, (void*)(xg + (size_t)c * 2457600), 4096, 600, 300, 300, 300, 600, bi, bh);
  }
  lstm_scan<<<4, 1024, 0, stream>>>(solv_Whh, solu_Whh, xg, Hb, Gb, 1);

  // attention
  attn_stats<<<dim3(8, 64), 256, 0, stream>>>(Hb, Gb, pm, pl);
  stats_combine<<<16, 256, 0, stream>>>(pm, pl, mr, il);
  gemm_k<0, float, 1><<<dim3(64, 64), 256, 0, stream>>>(
      Hb, Gb, (void*)AH, 4096, 4096, 300, 300, 300, 4096, mr, il);
  gemm_k<1, __half, 0><<<dim3(5, 64), 256, 0, stream>>>(
      AH, Gb, (void*)Pb, 4096, 300, 4096, 4096, 300, 300, nullptr, nullptr);
  gemm_k<2, __half, 0><<<dim3(5, 64), 256, 0, stream>>>(
      AH, Hb, (void*)Qb, 4096, 300, 4096, 4096, 300, 300, nullptr, nullptr);

  // tail
  zero_inp<<<1, 640, 0, stream>>>(inp);
  reduce_uv<<<32, 320, 0, stream>>>(Hb, Pb, inp, 0);
  reduce_uv<<<32, 320, 0, stream>>>(Gb, Qb, inp, 300);
  fc1_k<<<8, 256, 0, stream>>>(fc1_w, fc1_b, inp, xf);
  fc2_k<<<1, 256, 0, stream>>>(xf, fc2_w, fc2_b, outp);
}

// Round 3
// 8070.922 us; speedup vs baseline: 1.4933x; 1.4933x over previous
//
#include <hip/hip_runtime.h>
#include <hip/hip_fp16.h>
#include <cstddef>

#define T_LEN 4096
#define HID 150
#define G4 600
#define NC 300

typedef __attribute__((ext_vector_type(8))) short bf16x8;   // 8 bf16 = 4 VGPRs
typedef __attribute__((ext_vector_type(4))) float f32x4;

// raw barrier: waits LDS ops only, leaves global loads/stores in flight
__device__ __forceinline__ void barrier_lgkm() {
  asm volatile("s_waitcnt lgkmcnt(0)\n\ts_barrier" ::: "memory");
}

__device__ __forceinline__ float fsig(float x) {
  return __builtin_amdgcn_rcpf(1.f + __expf(-x));
}
__device__ __forceinline__ float ftanh(float x) {
  float ax = fabsf(x);
  float e = __expf(2.f * ax);
  float t = 1.f - 2.f * __builtin_amdgcn_rcpf(e + 1.f);
  return copysignf(t, x);
}
__device__ __forceinline__ unsigned short f2bf(float f) {  // RNE fp32->bf16
  unsigned u = __builtin_bit_cast(unsigned, f);
  u += 0x7fff + ((u >> 16) & 1);
  return (unsigned short)(u >> 16);
}

// ---------------- LSTM scan via MFMA: 4 chains, one block (8 waves) each -------
// g[640] = h[160] @ WhhT as 16x16x32 bf16 MFMA, A row0 = h, rows 1-15 = 0.
// Wave w owns n-tiles {w+8j, j<5}; B-frags stay in unified VGPR/AGPR file and
// are read by MFMA directly (no per-use move cost, unlike fp32 arrays).
__global__ __launch_bounds__(512, 2) void lstm_scan(
    const float* __restrict__ whh_solv, const float* __restrict__ whh_solu,
    const float* __restrict__ xg_base,
    float* __restrict__ out_solv, float* __restrict__ out_solu, int layer)
{
  __shared__ __align__(16) unsigned short h_bf[160];  // bf16 h, zeros beyond 150
  __shared__ float g_s[640];
  const int c = blockIdx.x;
  const int net = c >> 1, dir = c & 1;
  const float* Whh = (net ? whh_solu : whh_solv) + (size_t)(layer * 2 + dir) * (G4 * HID);
  const float* xg = xg_base + (size_t)c * T_LEN * G4;
  float* out = (net ? out_solu : out_solv) + dir * HID;  // row stride NC
  const int tid = threadIdx.x;
  const int lane = tid & 63, wv = tid >> 6;
  const int lrow = lane & 15, lq = lane >> 4;  // frag row/col & k-quad

  // B-fragments: B[k][n] = WhhT[k][n] = Whh[n][k]; lane holds n=n0+lrow, k=kk*32+lq*8+i
  bf16x8 bfr[5][5];  // [j][kk]
#pragma unroll
  for (int j = 0; j < 5; j++) {
    const int jrow = 16 * (wv + 8 * j) + lrow;
#pragma unroll
    for (int kk = 0; kk < 5; kk++) {
      bf16x8 b;
#pragma unroll
      for (int i = 0; i < 8; i++) {
        const int k = kk * 32 + lq * 8 + i;
        const float v = (jrow < G4 && k < HID) ? Whh[(size_t)jrow * HID + k] : 0.f;
        b[i] = (short)f2bf(v);
      }
      bfr[j][kk] = b;
    }
  }
  if (tid < 160) h_bf[tid] = 0;
  float cst = 0.f;
  float xr0 = 0.f, xr1 = 0.f, xr2 = 0.f, xr3 = 0.f;
  if (tid < HID) {
    const int t0 = dir ? (T_LEN - 1) : 0;
    const float* xgr = xg + (size_t)t0 * G4 + tid;
    xr0 = xgr[0]; xr1 = xgr[HID]; xr2 = xgr[2 * HID]; xr3 = xgr[3 * HID];
  }
  barrier_lgkm();

  for (int s = 0; s < T_LEN; s++) {
    const int t = dir ? (T_LEN - 1 - s) : s;
    // A-frags: row0 = h_bf, rows 1-15 zero -> only lanes with lrow==0 load
    bf16x8 af[5];
#pragma unroll
    for (int kk = 0; kk < 5; kk++) {
      bf16x8 a = {0, 0, 0, 0, 0, 0, 0, 0};
      if (lrow == 0) a = *(const bf16x8*)&h_bf[kk * 32 + lq * 8];
      af[kk] = a;
    }
    f32x4 acc[5];
#pragma unroll
    for (int j = 0; j < 5; j++) acc[j] = (f32x4){0.f, 0.f, 0.f, 0.f};
#pragma unroll
    for (int kk = 0; kk < 5; kk++)
#pragma unroll
      for (int j = 0; j < 5; j++)
        acc[j] = __builtin_amdgcn_mfma_f32_16x16x32_bf16(af[kk], bfr[j][kk], acc[j], 0, 0, 0);
    // D row0 lives in lanes 0-15, reg 0
    if (lane < 16) {
#pragma unroll
      for (int j = 0; j < 5; j++) g_s[16 * (wv + 8 * j) + lane] = acc[j][0];
    }
    barrier_lgkm();
    if (tid < HID) {
      const int n = tid;
      float gi = xr0 + g_s[n];
      float gf = xr1 + g_s[HID + n];
      float gg = xr2 + g_s[2 * HID + n];
      float go = xr3 + g_s[3 * HID + n];
      if (s + 1 < T_LEN) {  // prefetch next xg row (global loads stay in flight past barrier)
        const int tn = dir ? (T_LEN - 2 - s) : (s + 1);
        const float* xgr = xg + (size_t)tn * G4 + n;
        xr0 = xgr[0]; xr1 = xgr[HID]; xr2 = xgr[2 * HID]; xr3 = xgr[3 * HID];
      }
      const float iv = fsig(gi), fv = fsig(gf), gv = ftanh(gg), ov = fsig(go);
      cst = fv * cst + iv * gv;
      const float hv = ov * ftanh(cst);
      h_bf[n] = f2bf(hv);      // matvec input rounded; c/h state stays fp32
      out[(size_t)t * NC + n] = hv;
    }
    barrier_lgkm();
  }
}

// ---------------- generic tiled fp32 GEMM -------------------------------------
// MODE: 0 = NT (C=A*B^T), 1 = NN, 2 = TN.  EPI: 0 = float C (+bias e0[n]+e1[n] if e0),
// 1 = half C = exp(acc - e0[m]) * e1[m]
__device__ __forceinline__ float to_f(float v) { return v; }
__device__ __forceinline__ float to_f(__half v) { return __half2float(v); }

#define LP 68  // LDS row pitch: 272 B (16B-aligned rows, breaks stride-64 bank conflicts)

template <int MODE, typename TA, int EPI>
__global__ void gemm_k(const TA* __restrict__ A, const float* __restrict__ B,
                       void* __restrict__ Cv, int M, int N, int K,
                       int lda, int ldb, int ldc,
                       const float* __restrict__ e0, const float* __restrict__ e1)
{
  __shared__ __align__(16) float As[16][LP];
  __shared__ __align__(16) float Bs[16][LP];
  const int tid = threadIdx.x;
  const int tx = tid & 15, ty = tid >> 4;
  const int m0 = blockIdx.y * 64, n0 = blockIdx.x * 64;
  float acc[4][4] = {};
  for (int kc = 0; kc < K; kc += 16) {
#pragma unroll
    for (int j = 0; j < 4; j++) {
      const int li = tid * 4 + j;
      int ml, kl;
      if (MODE == 2) { ml = li & 63; kl = li >> 6; }
      else           { ml = li >> 4; kl = li & 15; }
      const int m = m0 + ml, k = kc + kl;
      float v = 0.f;
      if (m < M && k < K)
        v = to_f(MODE == 2 ? A[(size_t)k * lda + m] : A[(size_t)m * lda + k]);
      As[kl][ml] = v;
    }
#pragma unroll
    for (int j = 0; j < 4; j++) {
      const int li = tid * 4 + j;
      int nl, kl;
      if (MODE == 0) { nl = li >> 4; kl = li & 15; }
      else           { nl = li & 63; kl = li >> 6; }
      const int n = n0 + nl, k = kc + kl;
      float v = 0.f;
      if (n < N && k < K)
        v = (MODE == 0) ? B[(size_t)n * ldb + k] : B[(size_t)k * ldb + n];
      Bs[kl][nl] = v;
    }
    __syncthreads();
#pragma unroll
    for (int kl = 0; kl < 16; kl++) {
      const float4 av = *(const float4*)&As[kl][ty * 4];
      const float4 bv = *(const float4*)&Bs[kl][tx * 4];
      const float aa[4] = {av.x, av.y, av.z, av.w};
      const float bb[4] = {bv.x, bv.y, bv.z, bv.w};
#pragma unroll
      for (int i = 0; i < 4; i++)
#pragma unroll
        for (int jj = 0; jj < 4; jj++)
          acc[i][jj] += aa[i] * bb[jj];
    }
    __syncthreads();
  }
#pragma unroll
  for (int i = 0; i < 4; i++) {
    const int m = m0 + ty * 4 + i;
    if (m >= M) continue;
#pragma unroll
    for (int j = 0; j < 4; j++) {
      const int n = n0 + tx * 4 + j;
      if (n >= N) continue;
      if (EPI == 0) {
        float v = acc[i][j];
        if (e0) v += e0[n] + e1[n];
        ((float*)Cv)[(size_t)m * ldc + n] = v;
      } else {
        const float v = __expf(acc[i][j] - e0[m]) * e1[m];
        ((__half*)Cv)[(size_t)m * ldc + n] = __float2half(v);
      }
    }
  }
}

// ------------- attention softmax stats (never materializes S) -----------------
// grid (8 g-chunks, 64 h-blocks), block 256; writes partial (m,l) per row per chunk
__global__ void attn_stats(const float* __restrict__ Hm, const float* __restrict__ Gm,
                           float* __restrict__ pm, float* __restrict__ pl)
{
  __shared__ __align__(16) float As[16][LP];
  __shared__ __align__(16) float Bs[16][LP];
  const int tid = threadIdx.x;
  const int tx = tid & 15, ty = tid >> 4;
  const int m0 = blockIdx.y * 64;
  float rm[4], rl[4];
#pragma unroll
  for (int i = 0; i < 4; i++) { rm[i] = -3e38f; rl[i] = 0.f; }
  for (int nt = 0; nt < 8; nt++) {
    const int n0 = (blockIdx.x * 8 + nt) * 64;
    float acc[4][4] = {};
    for (int kc = 0; kc < NC; kc += 16) {
#pragma unroll
      for (int j = 0; j < 4; j++) {
        const int li = tid * 4 + j;
        const int ml = li >> 4, kl = li & 15;
        const int k = kc + kl;
        As[kl][ml] = (k < NC) ? Hm[(size_t)(m0 + ml) * NC + k] : 0.f;
        Bs[kl][ml] = (k < NC) ? Gm[(size_t)(n0 + ml) * NC + k] : 0.f;
      }
      __syncthreads();
#pragma unroll
      for (int kl = 0; kl < 16; kl++) {
        const float4 av = *(const float4*)&As[kl][ty * 4];
        const float4 bv = *(const float4*)&Bs[kl][tx * 4];
        const float aa[4] = {av.x, av.y, av.z, av.w};
        const float bb[4] = {bv.x, bv.y, bv.z, bv.w};
#pragma unroll
        for (int i = 0; i < 4; i++)
#pragma unroll
          for (int jj = 0; jj < 4; jj++)
            acc[i][jj] += aa[i] * bb[jj];
      }
      __syncthreads();
    }
#pragma unroll
    for (int i = 0; i < 4; i++) {
      const float mx = fmaxf(fmaxf(acc[i][0], acc[i][1]), fmaxf(acc[i][2], acc[i][3]));
      const float nm = fmaxf(rm[i], mx);
      const float s = __expf(acc[i][0] - nm) + __expf(acc[i][1] - nm) +
                      __expf(acc[i][2] - nm) + __expf(acc[i][3] - nm);
      rl[i] = rl[i] * __expf(rm[i] - nm) + s;
      rm[i] = nm;
    }
  }
  __syncthreads();
#pragma unroll
  for (int i = 0; i < 4; i++) { As[tx][ty * 4 + i] = rm[i]; Bs[tx][ty * 4 + i] = rl[i]; }
  __syncthreads();
  if (tid < 64) {
    float m = As[0][tid], l = Bs[0][tid];
#pragma unroll
    for (int c2 = 1; c2 < 16; c2++) {
      const float m2 = As[c2][tid], l2 = Bs[c2][tid];
      const float nm = fmaxf(m, m2);
      l = l * __expf(m - nm) + l2 * __expf(m2 - nm);
      m = nm;
    }
    pm[(size_t)(m0 + tid) * 8 + blockIdx.x] = m;
    pl[(size_t)(m0 + tid) * 8 + blockIdx.x] = l;
  }
}

__global__ void stats_combine(const float* __restrict__ pm, const float* __restrict__ pl,
                              float* __restrict__ mrow, float* __restrict__ invl)
{
  const int r = blockIdx.x * 256 + threadIdx.x;
  float m = -3e38f;
#pragma unroll
  for (int c2 = 0; c2 < 8; c2++) m = fmaxf(m, pm[r * 8 + c2]);
  float l = 0.f;
#pragma unroll
  for (int c2 = 0; c2 < 8; c2++) l += pl[r * 8 + c2] * __expf(pm[r * 8 + c2] - m);
  mrow[r] = m;
  invl[r] = 1.f / l;
}

// ---------------- tail ---------------------------------------------------------
__global__ void zero_inp(float* __restrict__ inp) {
  if (threadIdx.x < 600) inp[threadIdx.x] = 0.f;
}

__global__ void reduce_uv(const float* __restrict__ X, const float* __restrict__ Yp,
                          float* __restrict__ inp, int off)
{
  const int j = threadIdx.x;
  if (j >= NC) return;
  const int r0 = blockIdx.x * 128;
  float s = 0.f;
  for (int r = r0; r < r0 + 128; r++)
    s += fmaxf(X[(size_t)r * NC + j], Yp[(size_t)r * NC + j]);
  atomicAdd(&inp[off + j], s);
}

__global__ void fc1_k(const float* __restrict__ w1, const float* __restrict__ b1,
                      const float* __restrict__ inp, float* __restrict__ x)
{
  const int r = blockIdx.x * 256 + threadIdx.x;
  if (r >= 2000) return;
  float s = b1[r];
  const float* wr = w1 + (size_t)r * 600;
  for (int k = 0; k < 600; k++) s += wr[k] * inp[k];
  x[r] = fmaxf(s, 0.f);
}

__global__ void fc2_k(const float* __restrict__ x, const float* __restrict__ w2,
                      const float* __restrict__ b2, float* __restrict__ outp)
{
  const int tid = threadIdx.x;
  float s = 0.f;
  for (int i = tid; i < 2000; i += 256) s += x[i] * w2[i];
#pragma unroll
  for (int off = 32; off > 0; off >>= 1) s += __shfl_down(s, off);
  __shared__ float red[4];
  if ((tid & 63) == 0) red[tid >> 6] = s;
  __syncthreads();
  if (tid == 0) outp[0] = red[0] + red[1] + red[2] + red[3] + b2[0];
}

// ---------------- launch --------------------------------------------------------
extern "C" void kernel_launch(void* const* d_in, const int* in_sizes, int n_in,
                              void* d_out, int out_size, void* d_ws, size_t ws_size,
                              hipStream_t stream)
{
  const float* in_solv  = (const float*)d_in[0];
  const float* in_solu  = (const float*)d_in[1];
  const float* solv_Wih = (const float*)d_in[2];
  const float* solv_Whh = (const float*)d_in[3];
  const float* solv_bih = (const float*)d_in[4];
  const float* solv_bhh = (const float*)d_in[5];
  const float* solu_Wih = (const float*)d_in[6];
  const float* solu_Whh = (const float*)d_in[7];
  const float* solu_bih = (const float*)d_in[8];
  const float* solu_bhh = (const float*)d_in[9];
  const float* fc1_w = (const float*)d_in[10];
  const float* fc1_b = (const float*)d_in[11];
  const float* fc2_w = (const float*)d_in[12];
  const float* fc2_b = (const float*)d_in[13];
  float* outp = (float*)d_out;
  float* ws = (float*)d_ws;

  // workspace layout (float offsets); AH(half) aliases dead xg region. total ~69 MB
  constexpr size_t off_P   = 0;
  constexpr size_t off_Q   = 1228800;
  constexpr size_t off_inp = 2457600;
  constexpr size_t off_x   = 2458240;
  constexpr size_t off_pm  = 2460288;
  constexpr size_t off_pl  = 2493056;
  constexpr size_t off_mr  = 2525824;
  constexpr size_t off_il  = 2529920;
  constexpr size_t off_xg  = 2534016;
  constexpr size_t off_L0  = off_xg + (size_t)4 * 2457600;
  constexpr size_t off_HG  = off_L0 + (size_t)2 * 1228800;

  float* xg  = ws + off_xg;
  float* L0v = ws + off_L0;
  float* L0u = L0v + 1228800;
  float* Hb  = ws + off_HG;
  float* Gb  = Hb + 1228800;
  float* Pb  = ws + off_P;
  float* Qb  = ws + off_Q;
  float* inp = ws + off_inp;
  float* xf  = ws + off_x;
  float* pm  = ws + off_pm;
  float* pl  = ws + off_pl;
  float* mr  = ws + off_mr;
  float* il  = ws + off_il;
  __half* AH = (__half*)(ws + off_xg);

  // layer 0: xg = X @ Wih^T + (bih+bhh), 4 chains
  for (int c = 0; c < 4; c++) {
    const int net = c >> 1, d = c & 1;
    const float* X   = net ? in_solu : in_solv;
    const float* Wih = (net ? solu_Wih : solv_Wih) + (size_t)d * (600 * 300);
    const float* bi  = (net ? solu_bih : solv_bih) + (size_t)d * 600;
    const float* bh  = (net ? solu_bhh : solv_bhh) + (size_t)d * 600;
    gemm_k<0, float, 0><<<dim3(10, 64), 256, 0, stream>>>(
        X, Wih, (void*)(xg + (size_t)c * 2457600), 4096, 600, 300, 300, 300, 600, bi, bh);
  }
  lstm_scan<<<4, 512, 0, stream>>>(solv_Whh, solu_Whh, xg, L0v, L0u, 0);

  // layer 1
  for (int c = 0; c < 4; c++) {
    const int net = c >> 1, d = c & 1;
    const float* X   = net ? L0u : L0v;
    const float* Wih = (net ? solu_Wih : solv_Wih) + (size_t)(2 + d) * (600 * 300);
    const float* bi  = (net ? solu_bih : solv_bih) + (size_t)(2 + d) * 600;
    const float* bh  = (net ? solu_bhh : solv_bhh) + (size_t)(2 + d) * 600;
    gemm_k<0, float, 0><<<dim3(10, 64), 256, 0, stream>>>(
        X, Wih, (void*)(xg + (size_t)c * 2457600), 4096, 600, 300, 300, 300, 600, bi, bh);
  }
  lstm_scan<<<4, 512, 0, stream>>>(solv_Whh, solu_Whh, xg, Hb, Gb, 1);

  // attention
  attn_stats<<<dim3(8, 64), 256, 0, stream>>>(Hb, Gb, pm, pl);
  stats_combine<<<16, 256, 0, stream>>>(pm, pl, mr, il);
  gemm_k<0, float, 1><<<dim3(64, 64), 256, 0, stream>>>(
      Hb, Gb, (void*)AH, 4096, 4096, 300, 300, 300, 4096, mr, il);
  gemm_k<1, __half, 0><<<dim3(5, 64), 256, 0, stream>>>(
      AH, Gb, (void*)Pb, 4096, 300, 4096, 4096, 300, 300, nullptr, nullptr);
  gemm_k<2, __half, 0><<<dim3(5, 64), 256, 0, stream>>>(
      AH, Hb, (void*)Qb, 4096, 300, 4096, 4096, 300, 300, nullptr, nullptr);

  // tail
  zero_inp<<<1, 640, 0, stream>>>(inp);
  reduce_uv<<<32, 320, 0, stream>>>(Hb, Pb, inp, 0);
  reduce_uv<<<32, 320, 0, stream>>>(Gb, Qb, inp, 300);
  fc1_k<<<8, 256, 0, stream>>>(fc1_w, fc1_b, inp, xf);
  fc2_k<<<1, 256, 0, stream>>>(xf, fc2_w, fc2_b, outp);
}

// Round 5
// 7671.799 us; speedup vs baseline: 1.5710x; 1.0520x over previous
//
#include <hip/hip_runtime.h>
#include <hip/hip_fp16.h>
#include <cstddef>

#define T_LEN 4096
#define HID 150
#define G4 600
#define NC 300

typedef __attribute__((ext_vector_type(8))) short bf16x8;      // 8 bf16 = 4 VGPRs
typedef __attribute__((ext_vector_type(8))) _Float16 f16x8;    // 8 fp16 = 4 VGPRs
typedef __attribute__((ext_vector_type(4))) float f32x4;

// raw barrier: waits LDS ops only, leaves global loads/stores in flight
__device__ __forceinline__ void barrier_lgkm() {
  asm volatile("s_waitcnt lgkmcnt(0)\n\ts_barrier" ::: "memory");
}

__device__ __forceinline__ float fsig(float x) {
  return __builtin_amdgcn_rcpf(1.f + __expf(-x));
}
__device__ __forceinline__ float ftanh(float x) {
  float ax = fabsf(x);
  float e = __expf(2.f * ax);
  float t = 1.f - 2.f * __builtin_amdgcn_rcpf(e + 1.f);
  return copysignf(t, x);
}
__device__ __forceinline__ unsigned short f2bf(float f) {  // RNE fp32->bf16
  unsigned u = __builtin_bit_cast(unsigned, f);
  u += 0x7fff + ((u >> 16) & 1);
  return (unsigned short)(u >> 16);
}

// ---------------- LSTM scan via MFMA: 4 chains, one block (8 waves) each -------
// g[640] = h[160] @ WhhT as 16x16x32 bf16 MFMA, A row0 = h, rows 1-15 = 0.
// Matrix-pipe floor ~970 cyc/step (16x M-waste is structural for matvec).
__global__ __launch_bounds__(512, 2) void lstm_scan(
    const float* __restrict__ whh_solv, const float* __restrict__ whh_solu,
    const float* __restrict__ xg_base,
    float* __restrict__ out_solv, float* __restrict__ out_solu, int layer)
{
  __shared__ __align__(16) unsigned short h_bf[160];  // bf16 h, zeros beyond 150
  __shared__ float g_s[640];
  const int c = blockIdx.x;
  const int net = c >> 1, dir = c & 1;
  const float* Whh = (net ? whh_solu : whh_solv) + (size_t)(layer * 2 + dir) * (G4 * HID);
  const float* xg = xg_base + (size_t)c * T_LEN * G4;
  float* out = (net ? out_solu : out_solv) + dir * HID;  // row stride NC
  const int tid = threadIdx.x;
  const int lane = tid & 63, wv = tid >> 6;
  const int lrow = lane & 15, lq = lane >> 4;  // frag row & k-quad

  // B-fragments: B[k][n] = Whh[n][k]; lane holds n=16*tile+lrow, k=kk*32+lq*8+i
  bf16x8 bfr[5][5];  // [j][kk]
#pragma unroll
  for (int j = 0; j < 5; j++) {
    const int jrow = 16 * (wv + 8 * j) + lrow;
#pragma unroll
    for (int kk = 0; kk < 5; kk++) {
      bf16x8 b;
#pragma unroll
      for (int i = 0; i < 8; i++) {
        const int k = kk * 32 + lq * 8 + i;
        const float v = (jrow < G4 && k < HID) ? Whh[(size_t)jrow * HID + k] : 0.f;
        b[i] = (short)f2bf(v);
      }
      bfr[j][kk] = b;
    }
  }
  if (tid < 160) h_bf[tid] = 0;
  float cst = 0.f;
  float xr0 = 0.f, xr1 = 0.f, xr2 = 0.f, xr3 = 0.f;
  if (tid < HID) {
    const int t0 = dir ? (T_LEN - 1) : 0;
    const float* xgr = xg + (size_t)t0 * G4 + tid;
    xr0 = xgr[0]; xr1 = xgr[HID]; xr2 = xgr[2 * HID]; xr3 = xgr[3 * HID];
  }
  // A-frags hoisted: zeros persist in lanes lrow!=0; masked ds_read refreshes row 0
  bf16x8 af[5];
#pragma unroll
  for (int kk = 0; kk < 5; kk++) af[kk] = (bf16x8){0, 0, 0, 0, 0, 0, 0, 0};
  const f32x4 z4 = {0.f, 0.f, 0.f, 0.f};
  barrier_lgkm();

  for (int s = 0; s < T_LEN; s++) {
    const int t = dir ? (T_LEN - 1 - s) : s;
    if (lrow == 0) {
#pragma unroll
      for (int kk = 0; kk < 5; kk++) af[kk] = *(const bf16x8*)&h_bf[kk * 32 + lq * 8];
    }
    f32x4 acc[5];
#pragma unroll
    for (int j = 0; j < 5; j++)
      acc[j] = __builtin_amdgcn_mfma_f32_16x16x32_bf16(af[0], bfr[j][0], z4, 0, 0, 0);
#pragma unroll
    for (int kk = 1; kk < 5; kk++)
#pragma unroll
      for (int j = 0; j < 5; j++)
        acc[j] = __builtin_amdgcn_mfma_f32_16x16x32_bf16(af[kk], bfr[j][kk], acc[j], 0, 0, 0);
    // D row0 lives in lanes 0-15, reg 0
    if (lane < 16) {
#pragma unroll
      for (int j = 0; j < 5; j++) g_s[16 * (wv + 8 * j) + lane] = acc[j][0];
    }
    barrier_lgkm();
    if (tid < HID) {
      const int n = tid;
      float gi = xr0 + g_s[n];
      float gf = xr1 + g_s[HID + n];
      float gg = xr2 + g_s[2 * HID + n];
      float go = xr3 + g_s[3 * HID + n];
      if (s + 1 < T_LEN) {  // prefetch next xg row (stays in flight past barrier)
        const int tn = dir ? (T_LEN - 2 - s) : (s + 1);
        const float* xgr = xg + (size_t)tn * G4 + n;
        xr0 = xgr[0]; xr1 = xgr[HID]; xr2 = xgr[2 * HID]; xr3 = xgr[3 * HID];
      }
      const float iv = fsig(gi), fv = fsig(gf), gv = ftanh(gg), ov = fsig(go);
      cst = fv * cst + iv * gv;
      const float hv = ov * ftanh(cst);
      h_bf[n] = f2bf(hv);      // matvec input rounded; c/h state stays fp32
      out[(size_t)t * NC + n] = hv;
    }
    barrier_lgkm();
  }
}

// ---------------- fp32 -> fp16 conversion helpers ------------------------------
// Wihh[8][640][320]: slot s = l*4 + net*2 + dir, zero-padded rows/cols
__global__ void conv_w(const float* __restrict__ wv, const float* __restrict__ wu,
                       __half* __restrict__ dst)
{
  const int gid = blockIdx.x * 256 + threadIdx.x;
  if (gid >= 8 * 640 * 320) return;
  const int k = gid % 320, j = (gid / 320) % 640, s = gid / (320 * 640);
  const int l = s >> 2, net = (s >> 1) & 1, dir = s & 1;
  float v = 0.f;
  if (j < G4 && k < NC) {
    const float* src = (net ? wu : wv) + (size_t)(l * 2 + dir) * (G4 * NC);
    v = src[(size_t)j * NC + k];
  }
  dst[gid] = __float2half(v);
}

// X fp32 [rows][300] -> Xh fp16 [rows][320] zero-padded
__global__ void conv_x(const float* __restrict__ src, __half* __restrict__ dst, int rows)
{
  const int gid = blockIdx.x * 256 + threadIdx.x;
  if (gid >= rows * 320) return;
  const int k = gid % 320, m = gid / 320;
  dst[gid] = __float2half(k < NC ? src[(size_t)m * NC + k] : 0.f);
}

// X fp32 [4096][300] -> XT fp16 [320][4096] (rows >= 300 zeroed)
__global__ void conv_t(const float* __restrict__ src, __half* __restrict__ dst)
{
  const int gid = blockIdx.x * 256 + threadIdx.x;
  if (gid >= 320 * 4096) return;
  const int m = gid % 4096, f = gid / 4096;
  dst[gid] = __float2half(f < NC ? src[(size_t)m * NC + f] : 0.f);
}

__global__ void zero_f(float* __restrict__ p, int n) {
  const int i = blockIdx.x * 256 + threadIdx.x;
  if (i < n) p[i] = 0.f;
}

// ---------------- xg = X @ Wih^T + b via fp16 MFMA -----------------------------
// grid (64 m-blocks, 4 chains), block 256 (4 waves, 16 rows each). N=640, K=320.
__global__ __launch_bounds__(256) void xg_mfma(
    const __half* __restrict__ Av, const __half* __restrict__ Au,
    const __half* __restrict__ W,   // Wihh + layer*4*640*320
    const float* __restrict__ bihv, const float* __restrict__ bhhv,
    const float* __restrict__ bihu, const float* __restrict__ bhhu,
    float* __restrict__ xg, int layer)
{
  const int tid = threadIdx.x;
  const int lane = tid & 63, wv = tid >> 6;
  const int ln = lane & 15, q = lane >> 4;
  const int chain = blockIdx.y;
  const __half* A = (chain >= 2) ? Au : Av;
  const __half* Wc = W + (size_t)chain * 640 * 320;
  const float* bi = ((chain >= 2) ? bihu : bihv) + (size_t)(layer * 2 + (chain & 1)) * G4;
  const float* bh = ((chain >= 2) ? bhhu : bhhv) + (size_t)(layer * 2 + (chain & 1)) * G4;
  float* C = xg + (size_t)chain * T_LEN * G4;
  const int m0 = blockIdx.x * 64 + wv * 16;
  const __half* Arow = A + (size_t)(m0 + ln) * 320;

  for (int nc = 0; nc < 4; nc++) {       // 4 chunks x 160 cols
    f32x4 acc[10];
#pragma unroll
    for (int j = 0; j < 10; j++) acc[j] = (f32x4){0.f, 0.f, 0.f, 0.f};
    for (int kk = 0; kk < 10; kk++) {
      const f16x8 afr = *(const f16x8*)(Arow + kk * 32 + q * 8);
#pragma unroll
      for (int j = 0; j < 10; j++) {
        const int n = nc * 160 + j * 16 + ln;
        const f16x8 bfr = *(const f16x8*)(Wc + (size_t)n * 320 + kk * 32 + q * 8);
        acc[j] = __builtin_amdgcn_mfma_f32_16x16x32_f16(afr, bfr, acc[j], 0, 0, 0);
      }
    }
#pragma unroll
    for (int j = 0; j < 10; j++) {
      const int n = nc * 160 + j * 16 + ln;
      if (n < G4) {
        const float bias = bi[n] + bh[n];
#pragma unroll
        for (int r = 0; r < 4; r++)
          C[(size_t)(m0 + q * 4 + r) * G4 + n] = acc[j][r] + bias;
      }
    }
  }
}

// ------- attention pass 1: sums[m] = sum_n exp(S[m][n] - 30), S = Hh @ Gh^T ----
// grid (64 m-blocks, 4 n-quadrants), block 256. Softmax is shift-invariant: a
// global constant shift replaces per-row max machinery (clamp = overflow guard).
__global__ __launch_bounds__(256) void s_pass1(
    const __half* __restrict__ Hh, const __half* __restrict__ Gh,
    float* __restrict__ sums)
{
  const int tid = threadIdx.x;
  const int lane = tid & 63, wv = tid >> 6;
  const int ln = lane & 15, q = lane >> 4;
  const int m0 = blockIdx.x * 64 + wv * 16;
  const __half* Arow = Hh + (size_t)(m0 + ln) * 320;
  f16x8 afr[10];
#pragma unroll
  for (int kk = 0; kk < 10; kk++) afr[kk] = *(const f16x8*)(Arow + kk * 32 + q * 8);
  float rs[4] = {0.f, 0.f, 0.f, 0.f};
  const int nt0 = blockIdx.y * 64;
  for (int nt = 0; nt < 64; nt++) {
    const __half* Brow = Gh + (size_t)(16 * (nt0 + nt) + ln) * 320;
    f32x4 acc = (f32x4){0.f, 0.f, 0.f, 0.f};
#pragma unroll
    for (int kk = 0; kk < 10; kk++) {
      const f16x8 bfr = *(const f16x8*)(Brow + kk * 32 + q * 8);
      acc = __builtin_amdgcn_mfma_f32_16x16x32_f16(afr[kk], bfr, acc, 0, 0, 0);
    }
#pragma unroll
    for (int r = 0; r < 4; r++) rs[r] += __expf(fminf(acc[r] - 30.f, 80.f));
  }
#pragma unroll
  for (int m = 1; m <= 8; m <<= 1)
#pragma unroll
    for (int r = 0; r < 4; r++) rs[r] += __shfl_xor(rs[r], m);
  if (ln == 0) {
#pragma unroll
    for (int r = 0; r < 4; r++) atomicAdd(&sums[m0 + q * 4 + r], rs[r]);
  }
}

__global__ void invert_k(const float* __restrict__ sums, float* __restrict__ il) {
  const int i = blockIdx.x * 256 + threadIdx.x;
  if (i < 4096) il[i] = 1.f / sums[i];
}

// ------- attention pass 2: a = exp(S-30)*il[m] -> AH fp16 (row-major only) -----
__global__ __launch_bounds__(256) void s_pass2(
    const __half* __restrict__ Hh, const __half* __restrict__ Gh,
    const float* __restrict__ il, __half* __restrict__ AH)
{
  const int tid = threadIdx.x;
  const int lane = tid & 63, wv = tid >> 6;
  const int ln = lane & 15, q = lane >> 4;
  const int m0 = blockIdx.x * 64 + wv * 16;
  const __half* Arow = Hh + (size_t)(m0 + ln) * 320;
  f16x8 afr[10];
#pragma unroll
  for (int kk = 0; kk < 10; kk++) afr[kk] = *(const f16x8*)(Arow + kk * 32 + q * 8);
  float ilr[4];
#pragma unroll
  for (int r = 0; r < 4; r++) ilr[r] = il[m0 + q * 4 + r];
  const int nt0 = blockIdx.y * 64;
  for (int nt = 0; nt < 64; nt++) {
    const int n = 16 * (nt0 + nt) + ln;
    const __half* Brow = Gh + (size_t)n * 320;
    f32x4 acc = (f32x4){0.f, 0.f, 0.f, 0.f};
#pragma unroll
    for (int kk = 0; kk < 10; kk++) {
      const f16x8 bfr = *(const f16x8*)(Brow + kk * 32 + q * 8);
      acc = __builtin_amdgcn_mfma_f32_16x16x32_f16(afr[kk], bfr, acc, 0, 0, 0);
    }
#pragma unroll
    for (int r = 0; r < 4; r++) {
      const float a = __expf(fminf(acc[r] - 30.f, 80.f)) * ilr[r];
      AH[(size_t)(m0 + q * 4 + r) * 4096 + n] = __float2half(a);
    }
  }
}

// ------- P = AH @ GhT' : M=4096, N=320(store 300), K=4096; A read row-major ----
__global__ __launch_bounds__(256) void p_mfma(
    const __half* __restrict__ AH, const __half* __restrict__ GhT,
    float* __restrict__ Pb)
{
  const int tid = threadIdx.x;
  const int lane = tid & 63, wv = tid >> 6;
  const int ln = lane & 15, q = lane >> 4;
  const int m0 = blockIdx.x * 64 + wv * 16;
  const __half* Arow = AH + (size_t)(m0 + ln) * 4096;

  for (int nc = 0; nc < 2; nc++) {
    f32x4 acc[10];
#pragma unroll
    for (int j = 0; j < 10; j++) acc[j] = (f32x4){0.f, 0.f, 0.f, 0.f};
    for (int kk = 0; kk < 128; kk++) {
      const f16x8 afr = *(const f16x8*)(Arow + kk * 32 + q * 8);
#pragma unroll
      for (int j = 0; j < 10; j++) {
        const int n = nc * 160 + j * 16 + ln;
        const f16x8 bfr = *(const f16x8*)(GhT + (size_t)n * 4096 + kk * 32 + q * 8);
        acc[j] = __builtin_amdgcn_mfma_f32_16x16x32_f16(afr, bfr, acc[j], 0, 0, 0);
      }
    }
#pragma unroll
    for (int j = 0; j < 10; j++) {
      const int n = nc * 160 + j * 16 + ln;
      if (n < NC) {
#pragma unroll
        for (int r = 0; r < 4; r++)
          Pb[(size_t)(m0 + q * 4 + r) * NC + n] = acc[j][r];
      }
    }
  }
}

// ------- Q[j][f] = sum_i a[i][j] H[i][f]: a-operand transposed via LDS ---------
// grid 64 (j-blocks of 64), block 256 (4 waves, 16 j-rows each). K=4096 in 64-chunks.
__global__ __launch_bounds__(256) void qt_mfma(
    const __half* __restrict__ AH, const __half* __restrict__ HhT,
    float* __restrict__ Qb)
{
  __shared__ __align__(16) _Float16 Ats[64][72];  // [j-local][i-local], pitch 144 B
  const int tid = threadIdx.x;
  const int lane = tid & 63, wv = tid >> 6;
  const int ln = lane & 15, q = lane >> 4;
  const int j0 = blockIdx.x * 64;
  f32x4 acc[20];
#pragma unroll
  for (int j = 0; j < 20; j++) acc[j] = (f32x4){0.f, 0.f, 0.f, 0.f};
  const int il8 = tid >> 2, j8 = (tid & 3) * 16;  // staging role

  for (int ic = 0; ic < 4096; ic += 64) {
    __syncthreads();  // protect LDS tile reuse
    {
      const __half* src = AH + (size_t)(ic + il8) * 4096 + j0 + j8;
      const f16x8 v0 = *(const f16x8*)src;
      const f16x8 v1 = *(const f16x8*)(src + 8);
#pragma unroll
      for (int jj = 0; jj < 8; jj++) Ats[j8 + jj][il8] = v0[jj];
#pragma unroll
      for (int jj = 0; jj < 8; jj++) Ats[j8 + 8 + jj][il8] = v1[jj];
    }
    __syncthreads();
#pragma unroll
    for (int s = 0; s < 2; s++) {
      const f16x8 afr = *(const f16x8*)&Ats[wv * 16 + ln][s * 32 + q * 8];
      const __half* bbase = HhT + ic + s * 32 + q * 8;
#pragma unroll
      for (int j = 0; j < 20; j++) {
        const f16x8 bfr = *(const f16x8*)(bbase + (size_t)(j * 16 + ln) * 4096);
        acc[j] = __builtin_amdgcn_mfma_f32_16x16x32_f16(afr, bfr, acc[j], 0, 0, 0);
      }
    }
  }
#pragma unroll
  for (int j = 0; j < 20; j++) {
    const int f = j * 16 + ln;
    if (f < NC) {
#pragma unroll
      for (int r = 0; r < 4; r++)
        Qb[(size_t)(j0 + wv * 16 + q * 4 + r) * NC + f] = acc[j][r];
    }
  }
}

// ---------------- tail ---------------------------------------------------------
__global__ void reduce_uv(const float* __restrict__ X, const float* __restrict__ Yp,
                          float* __restrict__ inp, int off)
{
  const int j = threadIdx.x;
  if (j >= NC) return;
  const int r0 = blockIdx.x * 128;
  float s = 0.f;
  for (int r = r0; r < r0 + 128; r++)
    s += fmaxf(X[(size_t)r * NC + j], Yp[(size_t)r * NC + j]);
  atomicAdd(&inp[off + j], s);
}

__global__ void fc1_k(const float* __restrict__ w1, const float* __restrict__ b1,
                      const float* __restrict__ inp, float* __restrict__ x)
{
  const int r = blockIdx.x * 256 + threadIdx.x;
  if (r >= 2000) return;
  float s = b1[r];
  const float* wr = w1 + (size_t)r * 600;
  for (int k = 0; k < 600; k++) s += wr[k] * inp[k];
  x[r] = fmaxf(s, 0.f);
}

__global__ void fc2_k(const float* __restrict__ x, const float* __restrict__ w2,
                      const float* __restrict__ b2, float* __restrict__ outp)
{
  const int tid = threadIdx.x;
  float s = 0.f;
  for (int i = tid; i < 2000; i += 256) s += x[i] * w2[i];
#pragma unroll
  for (int off = 32; off > 0; off >>= 1) s += __shfl_down(s, off);
  __shared__ float red[4];
  if ((tid & 63) == 0) red[tid >> 6] = s;
  __syncthreads();
  if (tid == 0) outp[0] = red[0] + red[1] + red[2] + red[3] + b2[0];
}

// ---------------- launch --------------------------------------------------------
extern "C" void kernel_launch(void* const* d_in, const int* in_sizes, int n_in,
                              void* d_out, int out_size, void* d_ws, size_t ws_size,
                              hipStream_t stream)
{
  const float* in_solv  = (const float*)d_in[0];
  const float* in_solu  = (const float*)d_in[1];
  const float* solv_Wih = (const float*)d_in[2];
  const float* solv_Whh = (const float*)d_in[3];
  const float* solv_bih = (const float*)d_in[4];
  const float* solv_bhh = (const float*)d_in[5];
  const float* solu_Wih = (const float*)d_in[6];
  const float* solu_Whh = (const float*)d_in[7];
  const float* solu_bih = (const float*)d_in[8];
  const float* solu_bhh = (const float*)d_in[9];
  const float* fc1_w = (const float*)d_in[10];
  const float* fc1_b = (const float*)d_in[11];
  const float* fc2_w = (const float*)d_in[12];
  const float* fc2_b = (const float*)d_in[13];
  float* outp = (float*)d_out;
  float* ws = (float*)d_ws;

  // ---- workspace layout (float offsets); peak 17,214,080 fl = 68.9 MB
  //      (same footprint as the round-3 pass). Aliasing timeline commented.
  constexpr size_t off_P   = 0;          // Wihh (819,200 fl) early; P fp32 late
  constexpr size_t off_Q   = 1228800;    // Q fp32
  constexpr size_t off_inp = 2457600;    // 640
  constexpr size_t off_x   = 2458240;    // 2048
  constexpr size_t off_il  = 2460288;    // 4096
  constexpr size_t off_sm  = 2464384;    // 4096 (exp sums)
  constexpr size_t off_xg  = 2468480;    // xg 9,830,400 fl; later AH(8,388,608)+HhT/GhT(1,310,720)
  constexpr size_t off_L0  = off_xg + (size_t)4 * 2457600;   // L0v/L0u; earlier Avh/Auh; later Hh/Gh
  constexpr size_t off_HG  = off_L0 + (size_t)2 * 1228800;   // Hb/Gb; L0vh/L0uh transient

  float*  xg   = ws + off_xg;
  float*  L0v  = ws + off_L0;
  float*  L0u  = L0v + 1228800;
  float*  Hb   = ws + off_HG;
  float*  Gb   = Hb + 1228800;
  float*  Pb   = ws + off_P;
  float*  Qb   = ws + off_Q;
  float*  inp  = ws + off_inp;
  float*  xf   = ws + off_x;
  float*  il   = ws + off_il;
  float*  sums = ws + off_sm;
  __half* Wihh = (__half*)(ws + off_P);            // dead before P written
  __half* Avh  = (__half*)(ws + off_L0);           // dead before L0 written
  __half* Auh  = Avh + 4096 * 320;
  __half* L0vh = (__half*)(ws + off_HG);           // dead before Hb/Gb written
  __half* L0uh = L0vh + 4096 * 320;
  __half* Hh   = (__half*)(ws + off_L0);           // post-scan2 (L0 dead)
  __half* Gh   = Hh + 4096 * 320;
  __half* AH   = (__half*)(ws + off_xg);           // post-scan2 (xg dead); 8,388,608 fl
  __half* HhT  = AH + (size_t)4096 * 4096;         // +655,360 fl
  __half* GhT  = HhT + 320 * 4096;                 // +655,360 fl; total 9,699,328 < 9,830,400 ok

  // ---- weights + layer-0 inputs to fp16 ----
  conv_w<<<(8 * 640 * 320 + 255) / 256, 256, 0, stream>>>(solv_Wih, solu_Wih, Wihh);
  conv_x<<<(4096 * 320 + 255) / 256, 256, 0, stream>>>(in_solv, Avh, 4096);
  conv_x<<<(4096 * 320 + 255) / 256, 256, 0, stream>>>(in_solu, Auh, 4096);

  // ---- layer 0 ----
  xg_mfma<<<dim3(64, 4), 256, 0, stream>>>(Avh, Auh, Wihh,
      solv_bih, solv_bhh, solu_bih, solu_bhh, xg, 0);
  lstm_scan<<<4, 512, 0, stream>>>(solv_Whh, solu_Whh, xg, L0v, L0u, 0);

  // ---- layer 1 ----
  conv_x<<<(4096 * 320 + 255) / 256, 256, 0, stream>>>(L0v, L0vh, 4096);
  conv_x<<<(4096 * 320 + 255) / 256, 256, 0, stream>>>(L0u, L0uh, 4096);
  xg_mfma<<<dim3(64, 4), 256, 0, stream>>>(L0vh, L0uh, Wihh + (size_t)4 * 640 * 320,
      solv_bih, solv_bhh, solu_bih, solu_bhh, xg, 1);
  lstm_scan<<<4, 512, 0, stream>>>(solv_Whh, solu_Whh, xg, Hb, Gb, 1);

  // ---- attention (xg dead from here; AH/HhT/GhT live in its region) ----
  conv_x<<<(4096 * 320 + 255) / 256, 256, 0, stream>>>(Hb, Hh, 4096);
  conv_x<<<(4096 * 320 + 255) / 256, 256, 0, stream>>>(Gb, Gh, 4096);
  conv_t<<<(320 * 4096 + 255) / 256, 256, 0, stream>>>(Hb, HhT);
  conv_t<<<(320 * 4096 + 255) / 256, 256, 0, stream>>>(Gb, GhT);
  zero_f<<<16, 256, 0, stream>>>(sums, 4096);
  s_pass1<<<dim3(64, 4), 256, 0, stream>>>(Hh, Gh, sums);
  invert_k<<<16, 256, 0, stream>>>(sums, il);
  s_pass2<<<dim3(64, 4), 256, 0, stream>>>(Hh, Gh, il, AH);
  p_mfma<<<64, 256, 0, stream>>>(AH, GhT, Pb);
  qt_mfma<<<64, 256, 0, stream>>>(AH, HhT, Qb);

  // ---- tail ----
  zero_f<<<3, 256, 0, stream>>>(inp, 640);
  reduce_uv<<<32, 320, 0, stream>>>(Hb, Pb, inp, 0);
  reduce_uv<<<32, 320, 0, stream>>>(Gb, Qb, inp, 300);
  fc1_k<<<8, 256, 0, stream>>>(fc1_w, fc1_b, inp, xf);
  fc2_k<<<1, 256, 0, stream>>>(xf, fc2_w, fc2_b, outp);
}